// Round 7
// baseline (1081.873 us; speedup 1.0000x reference)
//
#include <hip/hip_runtime.h>
#include <hip/hip_fp16.h>

#define NFEAT_IN 21
#define NHID 16
#define NOUT 6
#define BSHIFT 7
#define BW (1 << BSHIFT)     // 128 nodes per bucket
#define NBMAX 2048           // supports n <= 262144
#define NSPLIT 4
#define SSH 16               // src phase = src >> 16  (0..3 for n <= 262144)
#define NSUB (NBMAX * NSPLIT)   // 8192 sub-buckets
#define EPT 32
#define PB 256
#define CHUNK (PB * EPT)     // 8192 edges per partition block

__global__ void k_zero(int* __restrict__ p, int n) {
    int i = blockIdx.x * blockDim.x + threadIdx.x;
    if (i < n) p[i] = 0;
}

// histogram over (dst-bucket, src-phase) sub-buckets
__global__ void k_hist(const int* __restrict__ src, const int* __restrict__ dst,
                       int* __restrict__ bcnt, int ne) {
    __shared__ int lcnt[NSUB];
    for (int t = threadIdx.x; t < NSUB; t += blockDim.x) lcnt[t] = 0;
    __syncthreads();
    int stride = gridDim.x * blockDim.x;
    for (int e = blockIdx.x * blockDim.x + threadIdx.x; e < ne; e += stride) {
        int d = dst[e], s = src[e];
        atomicAdd(&lcnt[(d >> BSHIFT) * NSPLIT + (s >> SSH)], 1);
    }
    __syncthreads();
    for (int t = threadIdx.x; t < NSUB; t += blockDim.x)
        if (lcnt[t]) atomicAdd(&bcnt[t], lcnt[t]);
}

// exclusive scan over NSUB entries: 1024 threads x 8 values
__global__ void k_scan(const int* __restrict__ bcnt, int* __restrict__ boff,
                       int* __restrict__ bcur) {
    __shared__ int s[1024];
    int t = threadIdx.x;
    int v[8];
    int sum = 0;
#pragma unroll
    for (int i = 0; i < 8; i++) { v[i] = bcnt[8 * t + i]; sum += v[i]; }
    s[t] = sum;
    __syncthreads();
    for (int off = 1; off < 1024; off <<= 1) {
        int tv = (t >= off) ? s[t - off] : 0;
        __syncthreads();
        s[t] += tv;
        __syncthreads();
    }
    int base = s[t] - sum;   // exclusive over chunks
#pragma unroll
    for (int i = 0; i < 8; i++) {
        boff[8 * t + i] = base;
        bcur[8 * t + i] = base;
        base += v[i];
    }
}

__global__ void k_partition(const int* __restrict__ src, const int* __restrict__ dst,
                            int* __restrict__ bcur, unsigned int* __restrict__ bucketed,
                            int ne) {
    __shared__ unsigned int ebd[CHUNK];   // (sub<<7)|dst_local
    __shared__ int lcnt[NSUB];            // reused: count -> write cursor
    int t = threadIdx.x;
    long base = (long)blockIdx.x * CHUNK;
    for (int b = t; b < NSUB; b += PB) lcnt[b] = 0;
    __syncthreads();
#pragma unroll
    for (int k = 0; k < EPT; k++) {
        int idx = t + k * PB;
        long e = base + idx;
        unsigned int v = 0xFFFFFFFFu;
        if (e < ne) {
            int d = dst[e], s = src[e];
            int sub = (d >> BSHIFT) * NSPLIT + (s >> SSH);
            v = ((unsigned int)sub << BSHIFT) | (unsigned int)(d & (BW - 1));
            atomicAdd(&lcnt[sub], 1);
        }
        ebd[idx] = v;
    }
    __syncthreads();
    for (int b = t; b < NSUB; b += PB) {
        int c = lcnt[b];
        int wbase = (c > 0) ? atomicAdd(&bcur[b], c) : 0;
        lcnt[b] = wbase;      // becomes cursor
    }
    __syncthreads();
#pragma unroll
    for (int k = 0; k < EPT; k++) {
        int idx = t + k * PB;
        unsigned int v = ebd[idx];
        if (v == 0xFFFFFFFFu) continue;
        int sub = v >> BSHIFT;
        int pos = atomicAdd(&lcnt[sub], 1);
        int s = src[base + idx];
        bucketed[pos] = ((unsigned int)s << BSHIFT) | (v & (BW - 1));
    }
}

__global__ void k_bucket_dinv(const unsigned int* __restrict__ bucketed,
                              const int* __restrict__ boff, const int* __restrict__ bcnt,
                              float* __restrict__ dinv, int n) {
    __shared__ int deg[BW];
    int b = blockIdx.x, t = threadIdx.x;
    if (t < BW) deg[t] = 0;
    __syncthreads();
    int e0 = boff[b * NSPLIT];
    int e1 = boff[b * NSPLIT + NSPLIT - 1] + bcnt[b * NSPLIT + NSPLIT - 1];
    for (int j = e0 + t; j < e1; j += blockDim.x)
        atomicAdd(&deg[bucketed[j] & (BW - 1)], 1);
    __syncthreads();
    if (t < BW) {
        int node = (b << BSHIFT) + t;
        if (node < n) dinv[node] = rsqrtf((float)deg[t] + 1.0f);
    }
}

// hs1h = fp16((x @ W1) * dinv[i]) — 16 halves (32B) per node
__global__ void k_dense1(const float* __restrict__ x, const float* __restrict__ W1,
                         const float* __restrict__ dinv, __half2* __restrict__ hs1h, int n) {
    __shared__ float sW[NFEAT_IN * NHID];
    for (int t = threadIdx.x; t < NFEAT_IN * NHID; t += blockDim.x) sW[t] = W1[t];
    __syncthreads();
    int i = blockIdx.x * blockDim.x + threadIdx.x;
    if (i >= n) return;
    float xi[NFEAT_IN];
#pragma unroll
    for (int k = 0; k < NFEAT_IN; k++) xi[k] = x[(size_t)i * NFEAT_IN + k];
    float di = dinv[i];
    float r[NHID];
#pragma unroll
    for (int j = 0; j < NHID; j++) {
        float acc = 0.f;
#pragma unroll
        for (int k = 0; k < NFEAT_IN; k++) acc += xi[k] * sW[k * NHID + j];
        r[j] = acc * di;
    }
    __half2* hp = hs1h + (size_t)i * 8;
#pragma unroll
    for (int q = 0; q < 8; q++) hp[q] = __floats2half2_rn(r[2 * q], r[2 * q + 1]);
}

__device__ __forceinline__ void acc16(float* a, uint4 u0, uint4 u1) {
    unsigned int us[8] = {u0.x, u0.y, u0.z, u0.w, u1.x, u1.y, u1.z, u1.w};
#pragma unroll
    for (int q = 0; q < 8; q++) {
        float2 f = __half22float2(*(const __half2*)&us[q]);
        atomicAdd(a + 2 * q, f.x);
        atomicAdd(a + 2 * q + 1, f.y);
    }
}

// bucket-centric aggregate layer1 + relu + dense2, src-phased for L2 residency
__global__ __launch_bounds__(256, 4) void
k_agg1(const unsigned int* __restrict__ bucketed, const int* __restrict__ boff,
       const int* __restrict__ bcnt, const __half2* __restrict__ hs1h,
       const float* __restrict__ b1, const float* __restrict__ W2,
       const float* __restrict__ dinv, __half2* __restrict__ hs2h, int n) {
    __shared__ float acc[BW * 17];
    __shared__ float sW[NHID * NOUT];
    __shared__ float sb[NHID];
    int b = blockIdx.x, t = threadIdx.x;
    for (int k = t; k < BW * 17; k += 256) acc[k] = 0.f;
    if (t < NHID * NOUT) sW[t] = W2[t];
    if (t < NHID) sb[t] = b1[t];
    __syncthreads();
    const char* hbase = (const char*)hs1h;
    // phased edge loop: all blocks sweep src-range phases in order so the
    // gather working set per phase (~2MB) is per-XCD-L2 resident
    for (int p = 0; p < NSPLIT; p++) {
        int sub = b * NSPLIT + p;
        int e0 = boff[sub], e1 = e0 + bcnt[sub];
        for (int j = e0 + t; j < e1; j += 256) {
            unsigned int pk = __builtin_nontemporal_load(bucketed + j);
            const uint4* a = (const uint4*)(hbase + (size_t)(pk >> BSHIFT) * 32);
            uint4 u0 = a[0], u1 = a[1];
            acc16(acc + (pk & (BW - 1)) * 17, u0, u1);
        }
        __syncthreads();   // keep waves phase-aligned
    }
    if (t >= BW) return;
    int node = (b << BSHIFT) + t;
    if (node >= n) return;
    float di = dinv[node];
    float z[NHID];
    {
        const uint4* sp = (const uint4*)(hbase + (size_t)node * 32);
        uint4 s0v = sp[0], s1v = sp[1];
        unsigned int us[8] = {s0v.x, s0v.y, s0v.z, s0v.w, s1v.x, s1v.y, s1v.z, s1v.w};
        float* a = acc + t * 17;
#pragma unroll
        for (int q = 0; q < 8; q++) {
            float2 f = __half22float2(*(const __half2*)&us[q]);
            z[2 * q]     = fmaxf((a[2 * q] + f.x) * di + sb[2 * q], 0.0f);
            z[2 * q + 1] = fmaxf((a[2 * q + 1] + f.y) * di + sb[2 * q + 1], 0.0f);
        }
    }
    float h[8];
#pragma unroll
    for (int kk = 0; kk < NOUT; kk++) {
        float s = 0.f;
#pragma unroll
        for (int jj = 0; jj < NHID; jj++) s += z[jj] * sW[jj * NOUT + kk];
        h[kk] = s * di;
    }
    h[6] = 0.f; h[7] = 0.f;
    __half2* op = hs2h + (size_t)node * 4;
#pragma unroll
    for (int q = 0; q < 4; q++) op[q] = __floats2half2_rn(h[2 * q], h[2 * q + 1]);
}

// bucket-centric aggregate layer2 + bias + log_softmax, src-phased
__global__ __launch_bounds__(256, 4) void
k_agg2(const unsigned int* __restrict__ bucketed, const int* __restrict__ boff,
       const int* __restrict__ bcnt, const __half2* __restrict__ hs2h,
       const float* __restrict__ b2, const float* __restrict__ dinv,
       float* __restrict__ out, int n) {
    __shared__ float acc[BW * 7];
    __shared__ float sb[NOUT];
    int b = blockIdx.x, t = threadIdx.x;
    for (int k = t; k < BW * 7; k += 256) acc[k] = 0.f;
    if (t < NOUT) sb[t] = b2[t];
    __syncthreads();
    const char* hbase = (const char*)hs2h;
    for (int p = 0; p < NSPLIT; p++) {
        int sub = b * NSPLIT + p;
        int e0 = boff[sub], e1 = e0 + bcnt[sub];
        for (int j = e0 + t; j < e1; j += 256) {
            unsigned int pk = __builtin_nontemporal_load(bucketed + j);
            uint4 u = *(const uint4*)(hbase + (size_t)(pk >> BSHIFT) * 16);
            float* a = acc + (pk & (BW - 1)) * 7;
            unsigned int us[3] = {u.x, u.y, u.z};
#pragma unroll
            for (int w = 0; w < 3; w++) {
                float2 fv = __half22float2(*(const __half2*)&us[w]);
                atomicAdd(a + 2 * w, fv.x);
                atomicAdd(a + 2 * w + 1, fv.y);
            }
        }
        __syncthreads();
    }
    if (t >= BW) return;
    int node = (b << BSHIFT) + t;
    if (node >= n) return;
    float di = dinv[node];
    uint4 sv = *(const uint4*)(hbase + (size_t)node * 16);
    unsigned int us[3] = {sv.x, sv.y, sv.z};
    float v[NOUT];
    float* a = acc + t * 7;
#pragma unroll
    for (int q = 0; q < 3; q++) {
        float2 f = __half22float2(*(const __half2*)&us[q]);
        v[2 * q]     = (a[2 * q] + f.x) * di + sb[2 * q];
        v[2 * q + 1] = (a[2 * q + 1] + f.y) * di + sb[2 * q + 1];
    }
    float m = -1e30f;
#pragma unroll
    for (int k = 0; k < NOUT; k++) m = fmaxf(m, v[k]);
    float se = 0.f;
#pragma unroll
    for (int k = 0; k < NOUT; k++) se += expf(v[k] - m);
    float l = logf(se);
#pragma unroll
    for (int k = 0; k < NOUT; k++) out[(size_t)node * NOUT + k] = v[k] - m - l;
}

extern "C" void kernel_launch(void* const* d_in, const int* in_sizes, int n_in,
                              void* d_out, int out_size, void* d_ws, size_t ws_size,
                              hipStream_t stream) {
    const float* x  = (const float*)d_in[0];
    const int*   ei = (const int*)d_in[1];
    const float* W1 = (const float*)d_in[2];
    const float* b1 = (const float*)d_in[3];
    const float* W2 = (const float*)d_in[4];
    const float* b2 = (const float*)d_in[5];
    float* out = (float*)d_out;

    int n  = in_sizes[0] / NFEAT_IN;   // 200000
    int ne = in_sizes[1] / 2;          // 6400000
    const int* src = ei;
    const int* dst = ei + ne;

    char* base = (char*)d_ws;
    size_t off = 0;
    auto alloc = [&](size_t bytes) {
        void* p = base + off;
        off += (bytes + 63) & ~(size_t)63;
        return p;
    };
    int* bcnt = (int*)alloc(NSUB * 4);
    int* boff = (int*)alloc(NSUB * 4);
    int* bcur = (int*)alloc(NSUB * 4);
    unsigned int* bucketed = (unsigned int*)alloc((size_t)ne * 4);
    float*   dinv = (float*)alloc((size_t)n * 4);
    __half2* hs1h = (__half2*)alloc((size_t)n * 32);
    __half2* hs2h = (__half2*)alloc((size_t)n * 16);

    int nb = (n + BW - 1) >> BSHIFT;          // 1563
    int gp = (ne + CHUNK - 1) / CHUNK;        // 782
    int gn = (n + 255) / 256;

    k_zero<<<(NSUB + 255) / 256, 256, 0, stream>>>(bcnt, NSUB);
    k_hist<<<256, 256, 0, stream>>>(src, dst, bcnt, ne);
    k_scan<<<1, 1024, 0, stream>>>(bcnt, boff, bcur);
    k_partition<<<gp, PB, 0, stream>>>(src, dst, bcur, bucketed, ne);
    k_bucket_dinv<<<nb, 256, 0, stream>>>(bucketed, boff, bcnt, dinv, n);
    k_dense1<<<gn, 256, 0, stream>>>(x, W1, dinv, hs1h, n);
    k_agg1<<<nb, 256, 0, stream>>>(bucketed, boff, bcnt, hs1h, b1, W2, dinv, hs2h, n);
    k_agg2<<<nb, 256, 0, stream>>>(bucketed, boff, bcnt, hs2h, b2, dinv, out, n);
}

// Round 9
// 1071.625 us; speedup vs baseline: 1.0096x; 1.0096x over previous
//
#include <hip/hip_runtime.h>
#include <hip/hip_fp16.h>

#define NFEAT_IN 21
#define NHID 16
#define NOUT 6
#define BSHIFT 7
#define BW (1 << BSHIFT)     // 128 nodes per bucket
#define NBMAX 2048           // supports n <= 262144
#define EPT 32
#define PB 256
#define CHUNK (PB * EPT)     // 8192 edges per partition block

__global__ void k_zero(int* __restrict__ p, int n) {
    int i = blockIdx.x * blockDim.x + threadIdx.x;
    if (i < n) p[i] = 0;
}

__global__ void k_hist(const int* __restrict__ dst, int* __restrict__ bcnt, int ne) {
    __shared__ int lcnt[NBMAX];
    for (int t = threadIdx.x; t < NBMAX; t += blockDim.x) lcnt[t] = 0;
    __syncthreads();
    int stride = gridDim.x * blockDim.x;
    for (int e = blockIdx.x * blockDim.x + threadIdx.x; e < ne; e += stride)
        atomicAdd(&lcnt[dst[e] >> BSHIFT], 1);
    __syncthreads();
    for (int t = threadIdx.x; t < NBMAX; t += blockDim.x)
        if (lcnt[t]) atomicAdd(&bcnt[t], lcnt[t]);
}

__global__ void k_scan(const int* __restrict__ bcnt, int* __restrict__ boff,
                       int* __restrict__ bcur) {
    __shared__ int s[1024];
    int t = threadIdx.x;
    int v0 = bcnt[2 * t], v1 = bcnt[2 * t + 1];
    int pair = v0 + v1;
    s[t] = pair;
    __syncthreads();
    for (int off = 1; off < 1024; off <<= 1) {
        int tv = (t >= off) ? s[t - off] : 0;
        __syncthreads();
        s[t] += tv;
        __syncthreads();
    }
    int ex = s[t] - pair;
    boff[2 * t] = ex;      bcur[2 * t] = ex;
    boff[2 * t + 1] = ex + v0;  bcur[2 * t + 1] = ex + v0;
}

__global__ void k_partition(const int* __restrict__ src, const int* __restrict__ dst,
                            int* __restrict__ bcur, unsigned int* __restrict__ bucketed,
                            int ne) {
    __shared__ unsigned int ebd[CHUNK];   // (bucket<<16)|dst_local
    __shared__ int lcnt[NBMAX];
    __shared__ int lbase[NBMAX];
    __shared__ int lcur[NBMAX];
    int t = threadIdx.x;
    long base = (long)blockIdx.x * CHUNK;
    for (int b = t; b < NBMAX; b += PB) lcnt[b] = 0;
    __syncthreads();
#pragma unroll
    for (int k = 0; k < EPT; k++) {
        int idx = t + k * PB;
        long e = base + idx;
        unsigned int v = 0xFFFF0000u;
        if (e < ne) {
            int d = dst[e];
            int b = d >> BSHIFT;
            v = ((unsigned int)b << 16) | (unsigned int)(d & (BW - 1));
            atomicAdd(&lcnt[b], 1);
        }
        ebd[idx] = v;
    }
    __syncthreads();
    for (int b = t; b < NBMAX; b += PB) {
        int c = lcnt[b];
        if (c > 0) lbase[b] = atomicAdd(&bcur[b], c);
        lcur[b] = 0;
    }
    __syncthreads();
#pragma unroll
    for (int k = 0; k < EPT; k++) {
        int idx = t + k * PB;
        unsigned int v = ebd[idx];
        unsigned int b = v >> 16;
        if (b == 0xFFFFu) continue;
        int r = atomicAdd(&lcur[b], 1);
        int s = src[base + idx];
        bucketed[lbase[b] + r] = ((unsigned int)s << BSHIFT) | (v & (BW - 1));
    }
}

__global__ void k_bucket_dinv(const unsigned int* __restrict__ bucketed,
                              const int* __restrict__ boff, const int* __restrict__ bcnt,
                              float* __restrict__ dinv, int n) {
    __shared__ int deg[BW];
    int b = blockIdx.x, t = threadIdx.x;
    if (t < BW) deg[t] = 0;
    __syncthreads();
    int s0 = boff[b], c = bcnt[b];
    for (int j = t; j < c; j += blockDim.x) atomicAdd(&deg[bucketed[s0 + j] & (BW - 1)], 1);
    __syncthreads();
    if (t < BW) {
        int node = (b << BSHIFT) + t;
        if (node < n) dinv[node] = rsqrtf((float)deg[t] + 1.0f);
    }
}

// hs1h = fp16((x @ W1) * dinv[i]) — 16 halves (32B) per node
__global__ void k_dense1(const float* __restrict__ x, const float* __restrict__ W1,
                         const float* __restrict__ dinv, __half2* __restrict__ hs1h, int n) {
    __shared__ float sW[NFEAT_IN * NHID];
    for (int t = threadIdx.x; t < NFEAT_IN * NHID; t += blockDim.x) sW[t] = W1[t];
    __syncthreads();
    int i = blockIdx.x * blockDim.x + threadIdx.x;
    if (i >= n) return;
    float xi[NFEAT_IN];
#pragma unroll
    for (int k = 0; k < NFEAT_IN; k++) xi[k] = x[(size_t)i * NFEAT_IN + k];
    float di = dinv[i];
    float r[NHID];
#pragma unroll
    for (int j = 0; j < NHID; j++) {
        float acc = 0.f;
#pragma unroll
        for (int k = 0; k < NFEAT_IN; k++) acc += xi[k] * sW[k * NHID + j];
        r[j] = acc * di;
    }
    __half2* hp = hs1h + (size_t)i * 8;
#pragma unroll
    for (int q = 0; q < 8; q++) hp[q] = __floats2half2_rn(r[2 * q], r[2 * q + 1]);
}

__device__ __forceinline__ void acc16(float* a, uint4 u0, uint4 u1) {
    unsigned int us[8] = {u0.x, u0.y, u0.z, u0.w, u1.x, u1.y, u1.z, u1.w};
#pragma unroll
    for (int q = 0; q < 8; q++) {
        float2 f = __half22float2(*(const __half2*)&us[q]);
        atomicAdd(a + 2 * q, f.x);
        atomicAdd(a + 2 * q + 1, f.y);
    }
}

// L1-bypass batched gathers. sc0 load: no L1 allocation -> escapes the per-CU
// L1 fill-concurrency cap (theory for the R3-R7 ~600us wall: ~8-10 outstanding
// line fills/CU). "=&v" early-clobber is REQUIRED: without it LLVM may place
// an output tuple on a later load's address pair (round-8 crash).
__device__ __forceinline__ void g8_sc0(const uint4* p0, const uint4* p1,
                                       const uint4* p2, const uint4* p3,
                                       const uint4* p4, const uint4* p5,
                                       const uint4* p6, const uint4* p7,
                                       uint4& r0, uint4& r1, uint4& r2, uint4& r3,
                                       uint4& r4, uint4& r5, uint4& r6, uint4& r7) {
    asm volatile(
        "global_load_dwordx4 %0, %8, off sc0\n\t"
        "global_load_dwordx4 %1, %9, off sc0\n\t"
        "global_load_dwordx4 %2, %10, off sc0\n\t"
        "global_load_dwordx4 %3, %11, off sc0\n\t"
        "global_load_dwordx4 %4, %12, off sc0\n\t"
        "global_load_dwordx4 %5, %13, off sc0\n\t"
        "global_load_dwordx4 %6, %14, off sc0\n\t"
        "global_load_dwordx4 %7, %15, off sc0\n\t"
        "s_waitcnt vmcnt(0)"
        : "=&v"(r0), "=&v"(r1), "=&v"(r2), "=&v"(r3),
          "=&v"(r4), "=&v"(r5), "=&v"(r6), "=&v"(r7)
        : "v"(p0), "v"(p1), "v"(p2), "v"(p3),
          "v"(p4), "v"(p5), "v"(p6), "v"(p7)
        : "memory");
}

__device__ __forceinline__ void g2_sc0(const uint4* p0, const uint4* p1,
                                       uint4& r0, uint4& r1) {
    asm volatile(
        "global_load_dwordx4 %0, %2, off sc0\n\t"
        "global_load_dwordx4 %1, %3, off sc0\n\t"
        "s_waitcnt vmcnt(0)"
        : "=&v"(r0), "=&v"(r1)
        : "v"(p0), "v"(p1)
        : "memory");
}

__device__ __forceinline__ void g1_sc0(const uint4* p0, uint4& r0) {
    asm volatile(
        "global_load_dwordx4 %0, %1, off sc0\n\t"
        "s_waitcnt vmcnt(0)"
        : "=&v"(r0)
        : "v"(p0)
        : "memory");
}

// bucket-centric aggregate layer1 + relu + dense2; 4-edge (8-load) sc0 batches
__global__ __launch_bounds__(256, 4) void
k_agg1(const unsigned int* __restrict__ bucketed, const int* __restrict__ boff,
       const int* __restrict__ bcnt, const __half2* __restrict__ hs1h,
       const float* __restrict__ b1, const float* __restrict__ W2,
       const float* __restrict__ dinv, __half2* __restrict__ hs2h, int n) {
    __shared__ float acc[BW * 17];
    __shared__ float sW[NHID * NOUT];
    __shared__ float sb[NHID];
    int b = blockIdx.x, t = threadIdx.x;
    for (int k = t; k < BW * 17; k += 256) acc[k] = 0.f;
    if (t < NHID * NOUT) sW[t] = W2[t];
    if (t < NHID) sb[t] = b1[t];
    __syncthreads();
    int s0 = boff[b], c = bcnt[b];
    const char* hbase = (const char*)hs1h;
    int j = s0 + t, jend = s0 + c;
    for (; j + 768 < jend; j += 1024) {
        unsigned int p0 = __builtin_nontemporal_load(bucketed + j);
        unsigned int p1 = __builtin_nontemporal_load(bucketed + j + 256);
        unsigned int p2 = __builtin_nontemporal_load(bucketed + j + 512);
        unsigned int p3 = __builtin_nontemporal_load(bucketed + j + 768);
        const uint4* q0 = (const uint4*)(hbase + (size_t)(p0 >> BSHIFT) * 32);
        const uint4* q1 = (const uint4*)(hbase + (size_t)(p1 >> BSHIFT) * 32);
        const uint4* q2 = (const uint4*)(hbase + (size_t)(p2 >> BSHIFT) * 32);
        const uint4* q3 = (const uint4*)(hbase + (size_t)(p3 >> BSHIFT) * 32);
        uint4 r0, r1, r2, r3, r4, r5, r6, r7;
        g8_sc0(q0, q0 + 1, q1, q1 + 1, q2, q2 + 1, q3, q3 + 1,
               r0, r1, r2, r3, r4, r5, r6, r7);
        acc16(acc + (p0 & (BW - 1)) * 17, r0, r1);
        acc16(acc + (p1 & (BW - 1)) * 17, r2, r3);
        acc16(acc + (p2 & (BW - 1)) * 17, r4, r5);
        acc16(acc + (p3 & (BW - 1)) * 17, r6, r7);
    }
    for (; j < jend; j += 256) {
        unsigned int p0 = __builtin_nontemporal_load(bucketed + j);
        const uint4* q0 = (const uint4*)(hbase + (size_t)(p0 >> BSHIFT) * 32);
        uint4 r0, r1;
        g2_sc0(q0, q0 + 1, r0, r1);
        acc16(acc + (p0 & (BW - 1)) * 17, r0, r1);
    }
    __syncthreads();
    if (t >= BW) return;
    int node = (b << BSHIFT) + t;
    if (node >= n) return;
    float di = dinv[node];
    float z[NHID];
    {
        const uint4* sp = (const uint4*)(hbase + (size_t)node * 32);
        uint4 s0v = sp[0], s1v = sp[1];
        unsigned int us[8] = {s0v.x, s0v.y, s0v.z, s0v.w, s1v.x, s1v.y, s1v.z, s1v.w};
        float* a = acc + t * 17;
#pragma unroll
        for (int q = 0; q < 8; q++) {
            float2 f = __half22float2(*(const __half2*)&us[q]);
            z[2 * q]     = fmaxf((a[2 * q] + f.x) * di + sb[2 * q], 0.0f);
            z[2 * q + 1] = fmaxf((a[2 * q + 1] + f.y) * di + sb[2 * q + 1], 0.0f);
        }
    }
    float h[8];
#pragma unroll
    for (int kk = 0; kk < NOUT; kk++) {
        float s = 0.f;
#pragma unroll
        for (int jj = 0; jj < NHID; jj++) s += z[jj] * sW[jj * NOUT + kk];
        h[kk] = s * di;
    }
    h[6] = 0.f; h[7] = 0.f;
    __half2* op = hs2h + (size_t)node * 4;
#pragma unroll
    for (int q = 0; q < 4; q++) op[q] = __floats2half2_rn(h[2 * q], h[2 * q + 1]);
}

__device__ __forceinline__ void acc6(float* a, uint4 u) {
    unsigned int us[3] = {u.x, u.y, u.z};
#pragma unroll
    for (int w = 0; w < 3; w++) {
        float2 fv = __half22float2(*(const __half2*)&us[w]);
        atomicAdd(a + 2 * w, fv.x);
        atomicAdd(a + 2 * w + 1, fv.y);
    }
}

// bucket-centric aggregate layer2 + bias + log_softmax; 8-edge (8-load) batches
__global__ __launch_bounds__(256, 4) void
k_agg2(const unsigned int* __restrict__ bucketed, const int* __restrict__ boff,
       const int* __restrict__ bcnt, const __half2* __restrict__ hs2h,
       const float* __restrict__ b2, const float* __restrict__ dinv,
       float* __restrict__ out, int n) {
    __shared__ float acc[BW * 7];
    __shared__ float sb[NOUT];
    int b = blockIdx.x, t = threadIdx.x;
    for (int k = t; k < BW * 7; k += 256) acc[k] = 0.f;
    if (t < NOUT) sb[t] = b2[t];
    __syncthreads();
    int s0 = boff[b], c = bcnt[b];
    const char* hbase = (const char*)hs2h;
    int j = s0 + t, jend = s0 + c;
    for (; j + 1792 < jend; j += 2048) {
        unsigned int pk[8];
#pragma unroll
        for (int q = 0; q < 8; q++)
            pk[q] = __builtin_nontemporal_load(bucketed + j + q * 256);
        const uint4* qp[8];
#pragma unroll
        for (int q = 0; q < 8; q++)
            qp[q] = (const uint4*)(hbase + (size_t)(pk[q] >> BSHIFT) * 16);
        uint4 r0, r1, r2, r3, r4, r5, r6, r7;
        g8_sc0(qp[0], qp[1], qp[2], qp[3], qp[4], qp[5], qp[6], qp[7],
               r0, r1, r2, r3, r4, r5, r6, r7);
        acc6(acc + (pk[0] & (BW - 1)) * 7, r0);
        acc6(acc + (pk[1] & (BW - 1)) * 7, r1);
        acc6(acc + (pk[2] & (BW - 1)) * 7, r2);
        acc6(acc + (pk[3] & (BW - 1)) * 7, r3);
        acc6(acc + (pk[4] & (BW - 1)) * 7, r4);
        acc6(acc + (pk[5] & (BW - 1)) * 7, r5);
        acc6(acc + (pk[6] & (BW - 1)) * 7, r6);
        acc6(acc + (pk[7] & (BW - 1)) * 7, r7);
    }
    for (; j < jend; j += 256) {
        unsigned int p0 = __builtin_nontemporal_load(bucketed + j);
        const uint4* q0 = (const uint4*)(hbase + (size_t)(p0 >> BSHIFT) * 16);
        uint4 r0;
        g1_sc0(q0, r0);
        acc6(acc + (p0 & (BW - 1)) * 7, r0);
    }
    __syncthreads();
    if (t >= BW) return;
    int node = (b << BSHIFT) + t;
    if (node >= n) return;
    float di = dinv[node];
    uint4 sv = *(const uint4*)(hbase + (size_t)node * 16);
    unsigned int us[3] = {sv.x, sv.y, sv.z};
    float v[NOUT];
    float* a = acc + t * 7;
#pragma unroll
    for (int q = 0; q < 3; q++) {
        float2 f = __half22float2(*(const __half2*)&us[q]);
        v[2 * q]     = (a[2 * q] + f.x) * di + sb[2 * q];
        v[2 * q + 1] = (a[2 * q + 1] + f.y) * di + sb[2 * q + 1];
    }
    float m = -1e30f;
#pragma unroll
    for (int k = 0; k < NOUT; k++) m = fmaxf(m, v[k]);
    float se = 0.f;
#pragma unroll
    for (int k = 0; k < NOUT; k++) se += expf(v[k] - m);
    float l = logf(se);
#pragma unroll
    for (int k = 0; k < NOUT; k++) out[(size_t)node * NOUT + k] = v[k] - m - l;
}

extern "C" void kernel_launch(void* const* d_in, const int* in_sizes, int n_in,
                              void* d_out, int out_size, void* d_ws, size_t ws_size,
                              hipStream_t stream) {
    const float* x  = (const float*)d_in[0];
    const int*   ei = (const int*)d_in[1];
    const float* W1 = (const float*)d_in[2];
    const float* b1 = (const float*)d_in[3];
    const float* W2 = (const float*)d_in[4];
    const float* b2 = (const float*)d_in[5];
    float* out = (float*)d_out;

    int n  = in_sizes[0] / NFEAT_IN;   // 200000
    int ne = in_sizes[1] / 2;          // 6400000
    const int* src = ei;
    const int* dst = ei + ne;

    char* base = (char*)d_ws;
    size_t off = 0;
    auto alloc = [&](size_t bytes) {
        void* p = base + off;
        off += (bytes + 63) & ~(size_t)63;
        return p;
    };
    int* bcnt = (int*)alloc(NBMAX * 4);
    int* boff = (int*)alloc(NBMAX * 4);
    int* bcur = (int*)alloc(NBMAX * 4);
    unsigned int* bucketed = (unsigned int*)alloc((size_t)ne * 4);
    float*   dinv = (float*)alloc((size_t)n * 4);
    __half2* hs1h = (__half2*)alloc((size_t)n * 32);
    __half2* hs2h = (__half2*)alloc((size_t)n * 16);

    int nb = (n + BW - 1) >> BSHIFT;          // 1563
    int gp = (ne + CHUNK - 1) / CHUNK;        // 782
    int gn = (n + 255) / 256;

    k_zero<<<(NBMAX + 255) / 256, 256, 0, stream>>>(bcnt, NBMAX);
    k_hist<<<256, 256, 0, stream>>>(dst, bcnt, ne);
    k_scan<<<1, 1024, 0, stream>>>(bcnt, boff, bcur);
    k_partition<<<gp, PB, 0, stream>>>(src, dst, bcur, bucketed, ne);
    k_bucket_dinv<<<nb, 256, 0, stream>>>(bucketed, boff, bcnt, dinv, n);
    k_dense1<<<gn, 256, 0, stream>>>(x, W1, dinv, hs1h, n);
    k_agg1<<<nb, 256, 0, stream>>>(bucketed, boff, bcnt, hs1h, b1, W2, dinv, hs2h, n);
    k_agg2<<<nb, 256, 0, stream>>>(bucketed, boff, bcnt, hs2h, b2, dinv, out, n);
}